// Round 4
// baseline (34408.655 us; speedup 1.0000x reference)
//
// ODE-RNN (B=128, F=512, I=128, H=512, O=1) on MI355X — Round 4.
// Structural change vs R3 (11.1 ms, L2-stream-bound at 83% of port ceiling):
// WEIGHTS LIVE IN REGISTERS. 16 blocks/group each own a 32-col shard of
// W1/W2/Whh/Wih = 208 VGPR/lane of frags (1 wave/SIMD budget is 512).
// Per stage: block computes its 32-col output shard from full activation
// (LDS), writes 2KB shard to an L2 exchange buffer, 16-block flag barrier
// (device-scope atomics, G16), gathers 32KB full activation back to LDS.
// G=4 groups x S=32 samples x 16 blocks = 64 blocks, 4 waves each, all
// co-resident (50KB LDS, <=1 block/CU by VGPR). Numerics identical to R3
// (same RK2 c=0.8 matched integrator, same bf16 rounding points).
// Predicted: 1.8-3.0 ms, barrier+gather latency bound; FETCH_SIZE -> <2GB.

#include <hip/hip_runtime.h>
#include <hip/hip_bf16.h>
#include <cstdint>
#include <cstddef>

#define HD 512
#define ID 128
#define FF 512
#define G 4          // sample groups
#define S 32         // samples per group
#define NBLK 16      // blocks per group (32-col weight shards)
#define AST 520      // LDS activation row stride (bf16 elems; 8-pad kills bank conflicts)
#define XST 136
#define NBAR (FF * 5)

typedef __bf16 bf16x8_t __attribute__((ext_vector_type(8)));
typedef unsigned short ushort8_t __attribute__((ext_vector_type(8)));
typedef float f32x4_t __attribute__((ext_vector_type(4)));

__device__ __forceinline__ unsigned short f2b(float x) {
  __hip_bfloat16 h = __float2bfloat16(x);
  return *reinterpret_cast<unsigned short*>(&h);
}
__device__ __forceinline__ bf16x8_t ld_frag(const unsigned short* p) {
  ushort8_t u = *reinterpret_cast<const ushort8_t*>(p);
  return __builtin_bit_cast(bf16x8_t, u);
}

// --- fp32 -> bf16 fragment-order pack (same layout as R3) -------------------
// dst[i]: i = ((colt*KT + kt)*64 + lane)*8 + j, KT = Kd/32.
// lane = n + 16*kq holds W[colt*16+n][kt*32 + kq*8 + j].
__global__ void pack_kernel(const float* __restrict__ in,
                            unsigned short* __restrict__ out, int Kd) {
  int i = blockIdx.x * blockDim.x + threadIdx.x;
  int total = HD * Kd;
  if (i >= total) return;
  int KT = Kd >> 5;
  int j = i & 7;
  int lane = (i >> 3) & 63;
  int t = i >> 9;
  int kt = t % KT;
  int colt = t / KT;
  int n = lane & 15, kq = lane >> 4;
  out[i] = f2b(in[(size_t)(colt * 16 + n) * Kd + kt * 32 + kq * 8 + j]);
}

__global__ void zero_kernel(unsigned int* __restrict__ p, int n) {
  int i = blockIdx.x * blockDim.x + threadIdx.x;
  if (i < n) p[i] = 0u;
}

// acc += A @ Wshard^T over K = KT*32, weights from registers.
template <int KT>
__device__ __forceinline__ f32x4_t mm_full(const bf16x8_t* wf,
                                           const unsigned short* arow,
                                           f32x4_t acc) {
#pragma unroll
  for (int kt = 0; kt < KT; ++kt) {
    bf16x8_t a = ld_frag(arow + kt * 32);
    acc = __builtin_amdgcn_mfma_f32_16x16x32_bf16(a, wf[kt], acc, 0, 0, 0);
  }
  return acc;
}

// --- the sequential recurrence ---------------------------------------------
__global__ __launch_bounds__(256, 1) void seq_kernel(
    const float* __restrict__ x, const float* __restrict__ tp,
    const float* __restrict__ b1, const float* __restrict__ b2,
    const float* __restrict__ bih, const float* __restrict__ bhh,
    const float* __restrict__ Wc,
    const unsigned short* __restrict__ W1p, const unsigned short* __restrict__ W2p,
    const unsigned short* __restrict__ Whhp, const unsigned short* __restrict__ Wihp,
    unsigned short* __restrict__ actg,   // G * 2 * S*512 bf16 exchange regions
    unsigned int* __restrict__ flags,    // G * NBAR counters
    float* __restrict__ logits) {        // 128 fp32, pre-zeroed
  __shared__ __align__(16) unsigned short actb[S][AST];  // full activation
  __shared__ __align__(16) unsigned short xb[S][XST];    // x_t
  __shared__ float h32[S][33];   // fp32 master h, own 32 cols (+pad)
  __shared__ float fsum[S][33];  // sum of post-RNN h, own cols
  __shared__ float scale[S];     // dt per sample
  __shared__ float redl[S][8];

  const int tid = threadIdx.x;
  const int wave = tid >> 6;
  const int lane = tid & 63;
  const int n = lane & 15;
  const int kq = lane >> 4;
  const int g = blockIdx.x >> 4;   // group
  const int j = blockIdx.x & 15;   // col-shard index
  const int ct = wave & 1;         // col-tile within shard
  const int rt = wave >> 1;        // row-tile (samples)
  const int colt = j * 2 + ct;     // global 16-col tile
  const int myc = j * 32 + ct * 16 + n;  // this lane's output column
  const int cl = ct * 16 + n;            // column local to shard
  const int s0 = g * S;

  // ---- weights into registers: 208 VGPR/lane ----
  bf16x8_t w1f[16], w2f[16], whhf[16], wihf[4];
#pragma unroll
  for (int kt = 0; kt < 16; ++kt) {
    w1f[kt]  = ld_frag(W1p  + (size_t)(colt * 16 + kt) * 512 + lane * 8);
    w2f[kt]  = ld_frag(W2p  + (size_t)(colt * 16 + kt) * 512 + lane * 8);
    whhf[kt] = ld_frag(Whhp + (size_t)(colt * 16 + kt) * 512 + lane * 8);
  }
#pragma unroll
  for (int kt = 0; kt < 4; ++kt)
    wihf[kt] = ld_frag(Wihp + (size_t)(colt * 4 + kt) * 512 + lane * 8);

  const float b1c = b1[myc];
  const float b2c = b2[myc];
  const float bbc = bih[myc] + bhh[myc];

  for (int i = tid; i < S * AST; i += 256) (&actb[0][0])[i] = 0;
  for (int i = tid; i < S * 33; i += 256) {
    (&h32[0][0])[i] = 0.f;
    (&fsum[0][0])[i] = 0.f;
  }
  __syncthreads();

  unsigned short* const myact = actg + (size_t)g * (2 * S * 512);
  unsigned int* const myflag = flags + (size_t)g * NBAR;
  int bar = 0;

  // barrier across the group's 16 blocks + gather full activation into actb
  auto xbar = [&]() {
    __threadfence();
    __syncthreads();
    if (tid == 0) {
      __hip_atomic_fetch_add(&myflag[bar], 1u, __ATOMIC_RELEASE,
                             __HIP_MEMORY_SCOPE_AGENT);
      while (__hip_atomic_load(&myflag[bar], __ATOMIC_ACQUIRE,
                               __HIP_MEMORY_SCOPE_AGENT) < (unsigned)NBLK)
        __builtin_amdgcn_s_sleep(1);
    }
    __syncthreads();
    __threadfence();
    const unsigned short* src = myact + (size_t)(bar & 1) * (S * 512);
    ushort8_t v[8];
#pragma unroll
    for (int rd = 0; rd < 8; ++rd) {
      int c = tid + rd * 256;
      v[rd] = *reinterpret_cast<const ushort8_t*>(src + c * 8);
    }
#pragma unroll
    for (int rd = 0; rd < 8; ++rd) {
      int c = tid + rd * 256;
      *reinterpret_cast<ushort8_t*>(&actb[c >> 6][(c & 63) * 8]) = v[rd];
    }
    __syncthreads();
    ++bar;
  };

#pragma unroll 1
  for (int f = 0; f < FF; ++f) {
    // stage x_t (bf16) and dt
    for (int i = tid; i < S * ID; i += 256) {
      int s = i >> 7, ii = i & (ID - 1);
      xb[s][ii] = f2b(x[((size_t)(s0 + s) * FF + f) * ID + ii]);
    }
    if (tid < S) {
      float d = (f > 0) ? (tp[(size_t)(s0 + tid) * FF + f] -
                           tp[(size_t)(s0 + tid) * FF + f - 1])
                        : 0.f;
      scale[tid] = d;
    }
    __syncthreads();

    const unsigned short* arow = &actb[rt * 16 + n][kq * 8];
    const unsigned short* xrow = &xb[rt * 16 + n][kq * 8];

    // ---- A: g = relu(h @ W1^T + b1) ----
    {
      f32x4_t acc = {0.f, 0.f, 0.f, 0.f};
      acc = mm_full<16>(w1f, arow, acc);
      unsigned short* dst = myact + (size_t)(bar & 1) * (S * 512);
#pragma unroll
      for (int r_ = 0; r_ < 4; ++r_) {
        int sl = rt * 16 + kq * 4 + r_;
        float y = acc[r_] + b1c;
        dst[sl * 512 + myc] = f2b(y > 0.f ? y : 0.f);
      }
      xbar();
    }
    // ---- B: k1 = g @ W2^T + b2; hb2 = h+0.8dt k1; h32 += 0.5dt k1 ----
    {
      f32x4_t acc = {0.f, 0.f, 0.f, 0.f};
      acc = mm_full<16>(w2f, arow, acc);
      unsigned short* dst = myact + (size_t)(bar & 1) * (S * 512);
#pragma unroll
      for (int r_ = 0; r_ < 4; ++r_) {
        int sl = rt * 16 + kq * 4 + r_;
        float k1 = acc[r_] + b2c;
        float ho = h32[sl][cl];
        float d = scale[sl];
        dst[sl * 512 + myc] = f2b(ho + 0.8f * d * k1);
        h32[sl][cl] = ho + 0.5f * d * k1;
      }
      xbar();
    }
    // ---- C: g2 = relu(hb2 @ W1^T + b1) ----
    {
      f32x4_t acc = {0.f, 0.f, 0.f, 0.f};
      acc = mm_full<16>(w1f, arow, acc);
      unsigned short* dst = myact + (size_t)(bar & 1) * (S * 512);
#pragma unroll
      for (int r_ = 0; r_ < 4; ++r_) {
        int sl = rt * 16 + kq * 4 + r_;
        float y = acc[r_] + b1c;
        dst[sl * 512 + myc] = f2b(y > 0.f ? y : 0.f);
      }
      xbar();
    }
    // ---- D: k2 = g2 @ W2^T + b2; h = h32 + 0.5dt k2 ----
    {
      f32x4_t acc = {0.f, 0.f, 0.f, 0.f};
      acc = mm_full<16>(w2f, arow, acc);
      unsigned short* dst = myact + (size_t)(bar & 1) * (S * 512);
#pragma unroll
      for (int r_ = 0; r_ < 4; ++r_) {
        int sl = rt * 16 + kq * 4 + r_;
        float k2 = acc[r_] + b2c;
        float h = h32[sl][cl] + 0.5f * scale[sl] * k2;
        h32[sl][cl] = h;
        dst[sl * 512 + myc] = f2b(h);
      }
      xbar();
    }
    // ---- RNN: h = tanh(x @ Wih^T + h' @ Whh^T + bih + bhh) ----
    {
      f32x4_t acc = {0.f, 0.f, 0.f, 0.f};
      acc = mm_full<4>(wihf, xrow, acc);
      acc = mm_full<16>(whhf, arow, acc);
      unsigned short* dst = myact + (size_t)(bar & 1) * (S * 512);
#pragma unroll
      for (int r_ = 0; r_ < 4; ++r_) {
        int sl = rt * 16 + kq * 4 + r_;
        float t = tanhf(acc[r_] + bbc);
        h32[sl][cl] = t;
        fsum[sl][cl] += t;
        dst[sl * 512 + myc] = f2b(t);
      }
      xbar();
    }
  }

  // ---- classifier partials: logits[s] += sum_own_cols fsum*Wc ----
  {
    int s = tid >> 3, q = tid & 7;
    float p = 0.f;
#pragma unroll
    for (int cc = q * 4; cc < q * 4 + 4; ++cc)
      p += fsum[s][cc] * Wc[j * 32 + cc];
    redl[s][q] = p;
  }
  __syncthreads();
  if (tid < S) {
    float v = 0.f;
#pragma unroll
    for (int q = 0; q < 8; ++q) v += redl[tid][q];
    atomicAdd(&logits[s0 + tid], v);
  }
}

__global__ void fin_kernel(const float* __restrict__ logits,
                           const float* __restrict__ bc,
                           float* __restrict__ out) {
  int b = threadIdx.x;
  if (b < 128) out[b] = 1.f / (1.f + __expf(-(logits[b] * (1.f / FF) + bc[0])));
}

// --- launch -----------------------------------------------------------------
extern "C" void kernel_launch(void* const* d_in, const int* in_sizes, int n_in,
                              void* d_out, int out_size, void* d_ws, size_t ws_size,
                              hipStream_t stream) {
  const float* x   = (const float*)d_in[0];
  const float* tp  = (const float*)d_in[1];
  const float* W1  = (const float*)d_in[2];
  const float* b1  = (const float*)d_in[3];
  const float* W2  = (const float*)d_in[4];
  const float* b2  = (const float*)d_in[5];
  const float* Wih = (const float*)d_in[6];
  const float* Whh = (const float*)d_in[7];
  const float* bih = (const float*)d_in[8];
  const float* bhh = (const float*)d_in[9];
  const float* Wc  = (const float*)d_in[10];
  const float* bc  = (const float*)d_in[11];
  float* out = (float*)d_out;

  unsigned short* W1p  = (unsigned short*)d_ws;
  unsigned short* W2p  = W1p + (size_t)HD * HD;
  unsigned short* Whhp = W2p + (size_t)HD * HD;
  unsigned short* Wihp = Whhp + (size_t)HD * HD;
  unsigned short* actg = Wihp + (size_t)HD * ID;           // G*2*S*512 bf16
  unsigned int*   flags = (unsigned int*)(actg + (size_t)G * 2 * S * 512);
  float*          logits = (float*)(flags + (size_t)G * NBAR);
  // total ws use ~1.92 MB

  pack_kernel<<<(HD * HD + 255) / 256, 256, 0, stream>>>(W1, W1p, HD);
  pack_kernel<<<(HD * HD + 255) / 256, 256, 0, stream>>>(W2, W2p, HD);
  pack_kernel<<<(HD * HD + 255) / 256, 256, 0, stream>>>(Whh, Whhp, HD);
  pack_kernel<<<(HD * ID + 255) / 256, 256, 0, stream>>>(Wih, Wihp, ID);
  int nz = G * NBAR + 128;
  zero_kernel<<<(nz + 255) / 256, 256, 0, stream>>>(flags, nz);

  seq_kernel<<<dim3(G * NBLK), dim3(256), 0, stream>>>(
      x, tp, b1, b2, bih, bhh, Wc, W1p, W2p, Whhp, Wihp, actg, flags, logits);
  fin_kernel<<<dim3(1), dim3(128), 0, stream>>>(logits, bc, out);
}

// Round 6
// 5338.475 us; speedup vs baseline: 6.4454x; 6.4454x over previous
//
// ODE-RNN (B=128, F=512, I=128, H=512, O=1) on MI355X — Round 6.
// R5 failed with a SMALL error (1.56e-2 ~ one-stage-stale activations): the
// exchange intermittently delivered stale data. No deadlock => flag RMW/poll
// path is fine; the data path had the hole. Two candidate holes:
//  T1: __syncthreads' fence is workgroup-scope and need not drain global
//      stores to L2 (shared write-through L1 suffices within a CU), so tid0's
//      flag RMW could reach L2 before sibling waves' data stores.
//  T2: agent-relaxed atomic LOADS may bypass the local L2 (sc1->MALL), reading
//      whatever was evicted rather than the producer's fresh L2 lines.
// R6 fixes BOTH, keeping same-XCD groups (the R5 perf idea, which is sound):
//  - explicit per-wave `s_waitcnt vmcnt(0)` after producer stores, BEFORE the
//    signal barrier (data provably in local L2 before any flag bump);
//  - gathers are PLAIN 16B loads (read local L2 where the write-through
//    stores live), preceded by `buffer_inv` + vmcnt(0) to kill stale L1 hits
//    (what R4's working __threadfence did for L1, minus the 13us L2 flush);
//  - flag bump/poll unchanged (agent-relaxed atomics, no fences).
// Weights remain in registers (208 VGPR/lane of frags). Numerics identical to
// R3/R4 (exact). Predicted: 2-4.5 ms; WRITE_SIZE < 50 MB; absmax ~0.

#include <hip/hip_runtime.h>
#include <hip/hip_bf16.h>
#include <cstdint>
#include <cstddef>

#define HD 512
#define ID 128
#define FF 512
#define G 4          // groups (each owns 32 samples)
#define S 32         // samples per group
#define NBLK 16      // blocks per group (32-col weight shards)
#define AST 520      // LDS activation row stride (bf16 elems)
#define XST 136
#define NBAR (FF * 5)
#define NLAUNCH 256  // blocks launched (>= 9 complete cohorts by pigeonhole)

// ctl word offsets (all zeroed before seq_kernel)
#define CT_TICKET 0          // [16] per-XCD ticket counters
#define CT_CLAIM 16          // group claim counter
#define CT_TOTAL 17          // registered-block counter
#define CT_MAP 20            // [256] cohort -> group+1 (0 = unclaimed)
#define CT_FLAGS 276         // [G*NBAR] barrier counters
#define CT_WORDS (276 + G * NBAR)

typedef __bf16 bf16x8_t __attribute__((ext_vector_type(8)));
typedef unsigned short ushort8_t __attribute__((ext_vector_type(8)));
typedef float f32x4_t __attribute__((ext_vector_type(4)));

__device__ __forceinline__ unsigned short f2b(float x) {
  __hip_bfloat16 h = __float2bfloat16(x);
  return *reinterpret_cast<unsigned short*>(&h);
}
__device__ __forceinline__ bf16x8_t ld_frag(const unsigned short* p) {
  ushort8_t u = *reinterpret_cast<const ushort8_t*>(p);
  return __builtin_bit_cast(bf16x8_t, u);
}

// --- fp32 -> bf16 fragment-order pack (same layout as R3-R5) ---------------
__global__ void pack_kernel(const float* __restrict__ in,
                            unsigned short* __restrict__ out, int Kd) {
  int i = blockIdx.x * blockDim.x + threadIdx.x;
  int total = HD * Kd;
  if (i >= total) return;
  int KT = Kd >> 5;
  int j = i & 7;
  int lane = (i >> 3) & 63;
  int t = i >> 9;
  int kt = t % KT;
  int colt = t / KT;
  int n = lane & 15, kq = lane >> 4;
  out[i] = f2b(in[(size_t)(colt * 16 + n) * Kd + kt * 32 + kq * 8 + j]);
}

__global__ void zero_kernel(unsigned int* __restrict__ p, int n) {
  int i = blockIdx.x * blockDim.x + threadIdx.x;
  if (i < n) p[i] = 0u;
}

// acc += A @ Wshard^T over K = KT*32, weights from registers.
template <int KT>
__device__ __forceinline__ f32x4_t mm_full(const bf16x8_t* wf,
                                           const unsigned short* arow,
                                           f32x4_t acc) {
#pragma unroll
  for (int kt = 0; kt < KT; ++kt) {
    bf16x8_t a = ld_frag(arow + kt * 32);
    acc = __builtin_amdgcn_mfma_f32_16x16x32_bf16(a, wf[kt], acc, 0, 0, 0);
  }
  return acc;
}

// --- the sequential recurrence ---------------------------------------------
__global__ __launch_bounds__(256, 1) void seq_kernel(
    const float* __restrict__ x, const float* __restrict__ tp,
    const float* __restrict__ b1, const float* __restrict__ b2,
    const float* __restrict__ bih, const float* __restrict__ bhh,
    const float* __restrict__ Wc,
    const unsigned short* __restrict__ W1p, const unsigned short* __restrict__ W2p,
    const unsigned short* __restrict__ Whhp, const unsigned short* __restrict__ Wihp,
    unsigned short* __restrict__ actg,   // G * 2 * S*512 bf16 exchange regions
    unsigned int* __restrict__ ctl,      // control words (see CT_*)
    float* __restrict__ logits) {        // 128 fp32, pre-zeroed
  __shared__ __align__(16) unsigned short actb[S][AST];  // full activation
  __shared__ __align__(16) unsigned short xb[S][XST];    // x_t
  __shared__ float h32[S][33];   // fp32 master h, own 32 cols (+pad)
  __shared__ float fsum[S][33];  // sum of post-RNN h, own cols
  __shared__ float scale[S];     // dt per sample
  __shared__ float redl[S][8];
  __shared__ int role[2];

  const int tid = threadIdx.x;

  // ---- XCD-aware registration & group claiming (tid 0 only) ----
  // Worked in R5 (no deadlock, full run): per-XCD ticket -> 16-cohort -> the
  // completer claims a global group id; first G claims become groups.
  if (tid == 0) {
    unsigned xcc;
    asm volatile("s_getreg_b32 %0, hwreg(HW_REG_XCC_ID, 0, 32)" : "=s"(xcc));
    const int xcd = (int)(xcc & 15u);
    unsigned rank = __hip_atomic_fetch_add(&ctl[CT_TICKET + xcd], 1u,
                                           __ATOMIC_RELAXED,
                                           __HIP_MEMORY_SCOPE_AGENT);
    const unsigned slot = (unsigned)xcd * 16u + (rank >> 4);
    if ((rank & 15u) == 15u) {  // cohort completer claims a group id
      unsigned gg = __hip_atomic_fetch_add(&ctl[CT_CLAIM], 1u,
                                           __ATOMIC_RELAXED,
                                           __HIP_MEMORY_SCOPE_AGENT);
      __hip_atomic_store(&ctl[CT_MAP + slot], gg + 1u, __ATOMIC_RELAXED,
                         __HIP_MEMORY_SCOPE_AGENT);
      asm volatile("s_waitcnt vmcnt(0)" ::: "memory");  // publish before total
    }
    __hip_atomic_fetch_add(&ctl[CT_TOTAL], 1u, __ATOMIC_RELAXED,
                           __HIP_MEMORY_SCOPE_AGENT);
    unsigned m;
    for (;;) {
      m = __hip_atomic_load(&ctl[CT_MAP + slot], __ATOMIC_RELAXED,
                            __HIP_MEMORY_SCOPE_AGENT);
      if (m) break;
      if (__hip_atomic_load(&ctl[CT_TOTAL], __ATOMIC_RELAXED,
                            __HIP_MEMORY_SCOPE_AGENT) >= (unsigned)NLAUNCH) {
        m = __hip_atomic_load(&ctl[CT_MAP + slot], __ATOMIC_RELAXED,
                              __HIP_MEMORY_SCOPE_AGENT);
        break;
      }
      __builtin_amdgcn_s_sleep(2);
    }
    role[0] = (m == 0 || m > (unsigned)G) ? -1 : (int)(m - 1);
    role[1] = (int)(rank & 15u);
  }
  __syncthreads();
  if (role[0] < 0) return;   // surplus / incomplete cohort: exit
  const int g = role[0];     // group id 0..3  (samples [g*32, g*32+32))
  const int j = role[1];     // 32-col weight shard 0..15

  const int wave = tid >> 6;
  const int lane = tid & 63;
  const int n = lane & 15;
  const int kq = lane >> 4;
  const int ct = wave & 1;         // col-tile within shard
  const int rt = wave >> 1;        // row-tile (samples)
  const int colt = j * 2 + ct;     // global 16-col tile
  const int myc = j * 32 + ct * 16 + n;  // this lane's output column
  const int cl = ct * 16 + n;            // column local to shard
  const int s0 = g * S;

  // ---- weights into registers: 208 VGPR/lane of frags ----
  bf16x8_t w1f[16], w2f[16], whhf[16], wihf[4];
#pragma unroll
  for (int kt = 0; kt < 16; ++kt) {
    w1f[kt]  = ld_frag(W1p  + (size_t)(colt * 16 + kt) * 512 + lane * 8);
    w2f[kt]  = ld_frag(W2p  + (size_t)(colt * 16 + kt) * 512 + lane * 8);
    whhf[kt] = ld_frag(Whhp + (size_t)(colt * 16 + kt) * 512 + lane * 8);
  }
#pragma unroll
  for (int kt = 0; kt < 4; ++kt)
    wihf[kt] = ld_frag(Wihp + (size_t)(colt * 4 + kt) * 512 + lane * 8);

  const float b1c = b1[myc];
  const float b2c = b2[myc];
  const float bbc = bih[myc] + bhh[myc];

  for (int i = tid; i < S * AST; i += 256) (&actb[0][0])[i] = 0;
  for (int i = tid; i < S * 33; i += 256) {
    (&h32[0][0])[i] = 0.f;
    (&fsum[0][0])[i] = 0.f;
  }
  __syncthreads();

  unsigned short* const myact = actg + (size_t)g * (2 * S * 512);
  unsigned int* const myflag = &ctl[CT_FLAGS + g * NBAR];
  int bar = 0;

  // Same-XCD exchange barrier + gather.
  // 1) per-wave vmcnt(0): this wave's producer stores are IN the local L2
  //    before it can contribute to the flag barrier (fixes T1);
  // 2) flag bump agent-relaxed RMW; poll agent-relaxed loads (proven in R5);
  // 3) buffer_inv + vmcnt(0): drop stale L1 lines, then PLAIN 16B gathers
  //    read the local L2 directly (fixes T2).
  auto xbar = [&]() {
    asm volatile("s_waitcnt vmcnt(0)" ::: "memory");
    __syncthreads();
    if (tid == 0) {
      __hip_atomic_fetch_add(&myflag[bar], 1u, __ATOMIC_RELAXED,
                             __HIP_MEMORY_SCOPE_AGENT);
      while (__hip_atomic_load(&myflag[bar], __ATOMIC_RELAXED,
                               __HIP_MEMORY_SCOPE_AGENT) < (unsigned)NBLK)
        __builtin_amdgcn_s_sleep(2);
    }
    __syncthreads();
    asm volatile("buffer_inv" ::: "memory");
    asm volatile("s_waitcnt vmcnt(0)" ::: "memory");
    const ushort8_t* src =
        (const ushort8_t*)(myact + (size_t)(bar & 1) * (S * 512));
    ushort8_t v[8];
#pragma unroll
    for (int rd = 0; rd < 8; ++rd) v[rd] = src[tid + rd * 256];
#pragma unroll
    for (int rd = 0; rd < 8; ++rd) {
      int c = tid + rd * 256;  // ushort8 unit index over [S][512]
      *reinterpret_cast<ushort8_t*>(&actb[c >> 6][(c & 63) * 8]) = v[rd];
    }
    __syncthreads();
    ++bar;
  };

#pragma unroll 1
  for (int f = 0; f < FF; ++f) {
    // stage x_t (bf16) and dt
    for (int i = tid; i < S * ID; i += 256) {
      int s = i >> 7, ii = i & (ID - 1);
      xb[s][ii] = f2b(x[((size_t)(s0 + s) * FF + f) * ID + ii]);
    }
    if (tid < S) {
      float d = (f > 0) ? (tp[(size_t)(s0 + tid) * FF + f] -
                           tp[(size_t)(s0 + tid) * FF + f - 1])
                        : 0.f;
      scale[tid] = d;
    }
    __syncthreads();

    const unsigned short* arow = &actb[rt * 16 + n][kq * 8];
    const unsigned short* xrow = &xb[rt * 16 + n][kq * 8];

    // ---- A: g = relu(h @ W1^T + b1) ----
    {
      f32x4_t acc = {0.f, 0.f, 0.f, 0.f};
      acc = mm_full<16>(w1f, arow, acc);
      unsigned short* dst = myact + (size_t)(bar & 1) * (S * 512);
#pragma unroll
      for (int r_ = 0; r_ < 4; ++r_) {
        int sl = rt * 16 + kq * 4 + r_;
        float y = acc[r_] + b1c;
        dst[sl * 512 + myc] = f2b(y > 0.f ? y : 0.f);
      }
      xbar();
    }
    // ---- B: k1 = g @ W2^T + b2; hb2 = h+0.8dt k1; h32 += 0.5dt k1 ----
    {
      f32x4_t acc = {0.f, 0.f, 0.f, 0.f};
      acc = mm_full<16>(w2f, arow, acc);
      unsigned short* dst = myact + (size_t)(bar & 1) * (S * 512);
#pragma unroll
      for (int r_ = 0; r_ < 4; ++r_) {
        int sl = rt * 16 + kq * 4 + r_;
        float k1 = acc[r_] + b2c;
        float ho = h32[sl][cl];
        float d = scale[sl];
        dst[sl * 512 + myc] = f2b(ho + 0.8f * d * k1);
        h32[sl][cl] = ho + 0.5f * d * k1;
      }
      xbar();
    }
    // ---- C: g2 = relu(hb2 @ W1^T + b1) ----
    {
      f32x4_t acc = {0.f, 0.f, 0.f, 0.f};
      acc = mm_full<16>(w1f, arow, acc);
      unsigned short* dst = myact + (size_t)(bar & 1) * (S * 512);
#pragma unroll
      for (int r_ = 0; r_ < 4; ++r_) {
        int sl = rt * 16 + kq * 4 + r_;
        float y = acc[r_] + b1c;
        dst[sl * 512 + myc] = f2b(y > 0.f ? y : 0.f);
      }
      xbar();
    }
    // ---- D: k2 = g2 @ W2^T + b2; h = h32 + 0.5dt k2 ----
    {
      f32x4_t acc = {0.f, 0.f, 0.f, 0.f};
      acc = mm_full<16>(w2f, arow, acc);
      unsigned short* dst = myact + (size_t)(bar & 1) * (S * 512);
#pragma unroll
      for (int r_ = 0; r_ < 4; ++r_) {
        int sl = rt * 16 + kq * 4 + r_;
        float k2 = acc[r_] + b2c;
        float h = h32[sl][cl] + 0.5f * scale[sl] * k2;
        h32[sl][cl] = h;
        dst[sl * 512 + myc] = f2b(h);
      }
      xbar();
    }
    // ---- RNN: h = tanh(x @ Wih^T + h' @ Whh^T + bih + bhh) ----
    {
      f32x4_t acc = {0.f, 0.f, 0.f, 0.f};
      acc = mm_full<4>(wihf, xrow, acc);
      acc = mm_full<16>(whhf, arow, acc);
      unsigned short* dst = myact + (size_t)(bar & 1) * (S * 512);
#pragma unroll
      for (int r_ = 0; r_ < 4; ++r_) {
        int sl = rt * 16 + kq * 4 + r_;
        float t = tanhf(acc[r_] + bbc);
        h32[sl][cl] = t;
        fsum[sl][cl] += t;
        dst[sl * 512 + myc] = f2b(t);
      }
      xbar();
    }
  }

  // ---- classifier partials: logits[s] += sum_own_cols fsum*Wc ----
  {
    int s = tid >> 3, q = tid & 7;
    float p = 0.f;
#pragma unroll
    for (int cc = q * 4; cc < q * 4 + 4; ++cc)
      p += fsum[s][cc] * Wc[j * 32 + cc];
    redl[s][q] = p;
  }
  __syncthreads();
  if (tid < S) {
    float v = 0.f;
#pragma unroll
    for (int q = 0; q < 8; ++q) v += redl[tid][q];
    atomicAdd(&logits[s0 + tid], v);   // device-scope, cross-XCD safe (m20)
  }
}

__global__ void fin_kernel(const float* __restrict__ logits,
                           const float* __restrict__ bc,
                           float* __restrict__ out) {
  int b = threadIdx.x;
  if (b < 128) out[b] = 1.f / (1.f + __expf(-(logits[b] * (1.f / FF) + bc[0])));
}

// --- launch -----------------------------------------------------------------
extern "C" void kernel_launch(void* const* d_in, const int* in_sizes, int n_in,
                              void* d_out, int out_size, void* d_ws, size_t ws_size,
                              hipStream_t stream) {
  const float* x   = (const float*)d_in[0];
  const float* tp  = (const float*)d_in[1];
  const float* W1  = (const float*)d_in[2];
  const float* b1  = (const float*)d_in[3];
  const float* W2  = (const float*)d_in[4];
  const float* b2  = (const float*)d_in[5];
  const float* Wih = (const float*)d_in[6];
  const float* Whh = (const float*)d_in[7];
  const float* bih = (const float*)d_in[8];
  const float* bhh = (const float*)d_in[9];
  const float* Wc  = (const float*)d_in[10];
  const float* bc  = (const float*)d_in[11];
  float* out = (float*)d_out;

  unsigned short* W1p  = (unsigned short*)d_ws;
  unsigned short* W2p  = W1p + (size_t)HD * HD;
  unsigned short* Whhp = W2p + (size_t)HD * HD;
  unsigned short* Wihp = Whhp + (size_t)HD * HD;
  unsigned short* actg = Wihp + (size_t)HD * ID;           // G*2*S*512 bf16
  unsigned int*   ctl  = (unsigned int*)(actg + (size_t)G * 2 * S * 512);
  float*          logits = (float*)(ctl + CT_WORDS);
  // total ws use ~2.0 MB

  pack_kernel<<<(HD * HD + 255) / 256, 256, 0, stream>>>(W1, W1p, HD);
  pack_kernel<<<(HD * HD + 255) / 256, 256, 0, stream>>>(W2, W2p, HD);
  pack_kernel<<<(HD * HD + 255) / 256, 256, 0, stream>>>(Whh, Whhp, HD);
  pack_kernel<<<(HD * ID + 255) / 256, 256, 0, stream>>>(Wih, Wihp, ID);
  int nz = CT_WORDS + 128;  // ctl + logits
  zero_kernel<<<(nz + 255) / 256, 256, 0, stream>>>(ctl, nz);

  seq_kernel<<<dim3(NLAUNCH), dim3(256), 0, stream>>>(
      x, tp, b1, b2, bih, bhh, Wc, W1p, W2p, Whhp, Wihp, actg, ctl, logits);
  fin_kernel<<<dim3(1), dim3(128), 0, stream>>>(logits, bc, out);
}